// Round 4
// baseline (360.031 us; speedup 1.0000x reference)
//
#include <hip/hip_runtime.h>
#include <hip/hip_bf16.h>
#include <hip/hip_cooperative_groups.h>
#include <cstdint>
#include <cstddef>

// ---------------------------------------------------------------------------
// Mamba block forward, MI355X (gfx950).  Round 4.
// Changes vs round 3:
//  - dtproj + scan_p1 + scan_p2 + scan_p3 fused into ONE cooperative kernel
//    (hipLaunchCooperativeKernel + grid.sync()); delta never materialized in
//    global (computed per-block via MFMA into LDS); u/B/C cached in LDS so
//    phase-3 replays from LDS only.  10 launches -> 7.
// ---------------------------------------------------------------------------

namespace cg = cooperative_groups;

typedef __attribute__((ext_vector_type(4))) float f32x4;
typedef __attribute__((ext_vector_type(8))) short short8;

#define GLOAD_LDS16(g, l)                                                      \
  __builtin_amdgcn_global_load_lds(                                            \
      (const __attribute__((address_space(1))) void*)(g),                      \
      (__attribute__((address_space(3))) void*)(l), 16, 0, 0)

__device__ __forceinline__ unsigned short f2bf(float f) {
  union { float f; unsigned u; } v; v.f = f;
  unsigned u = v.u;
  unsigned r = (u + 0x7FFFu + ((u >> 16) & 1u)) >> 16;  // round-to-nearest-even
  return (unsigned short)r;
}
__device__ __forceinline__ float bf2f(unsigned short u) {
  union { unsigned u; float f; } v; v.u = ((unsigned)u) << 16;
  return v.f;
}

// ---------------------------------------------------------------------------
// fp32 -> bf16 conversion for 5 arrays (blockIdx.y picks the array)
// ---------------------------------------------------------------------------
__global__ __launch_bounds__(256) void convert_all(
    const float* __restrict__ a0, unsigned short* __restrict__ o0, int n0,
    const float* __restrict__ a1, unsigned short* __restrict__ o1, int n1,
    const float* __restrict__ a2, unsigned short* __restrict__ o2, int n2,
    const float* __restrict__ a3, unsigned short* __restrict__ o3, int n3,
    const float* __restrict__ a4, unsigned short* __restrict__ o4, int n4) {
  const float* a; unsigned short* o; int n;
  switch (blockIdx.y) {
    case 0: a = a0; o = o0; n = n0; break;
    case 1: a = a1; o = o1; n = n1; break;
    case 2: a = a2; o = o2; n = n2; break;
    case 3: a = a3; o = o3; n = n3; break;
    default: a = a4; o = o4; n = n4; break;
  }
  int n4c = n >> 2;
  int stride = gridDim.x * blockDim.x;
  for (int i = blockIdx.x * blockDim.x + threadIdx.x; i < n4c; i += stride) {
    float4 v = ((const float4*)a)[i];
    uint2 p;
    p.x = (unsigned)f2bf(v.x) | ((unsigned)f2bf(v.y) << 16);
    p.y = (unsigned)f2bf(v.z) | ((unsigned)f2bf(v.w) << 16);
    ((uint2*)o)[i] = p;
  }
}

// ---------------------------------------------------------------------------
// 64x64-tile bf16 GEMM, C = A @ B^T.  Double-buffered LDS, global_load_lds,
// XOR k-slot swizzle (both sides), XCD-chunked bijective block swizzle.
// ---------------------------------------------------------------------------
template <int SPLITK, int OBF>
__global__ __launch_bounds__(256) void gemm64(
    const unsigned short* __restrict__ A, const unsigned short* __restrict__ B,
    void* __restrict__ Cv, int M, int N, int K) {
  __shared__ unsigned short lds[2][2][64 * 64];  // 32KB
  const int tid  = threadIdx.x;
  const int lane = tid & 63;
  const int w    = tid >> 6;

  // bijective XCD-chunked swizzle (requires gridDim.x % 8 == 0)
  const int nx = gridDim.x, ny = gridDim.y;
  int l = (blockIdx.z * ny + blockIdx.y) * nx + blockIdx.x;
  int xcd = l & 7, idx = l >> 3;
  int by = idx % ny;
  int r_ = idx / ny;
  int slab = nx >> 3;
  int bx = xcd * slab + (r_ % slab);
  int bz = r_ / slab;

  const int mBase = by * 64;
  const int nBase = bx * 64;
  const int kLen  = K / SPLITK;
  const int kBase = (SPLITK > 1) ? bz * kLen : 0;
  const int wr = (w >> 1) * 32;
  const int wc = (w & 1) * 32;
  const int wchunk = tid & 192;

  f32x4 acc[2][2];
  #pragma unroll
  for (int m = 0; m < 2; ++m)
    #pragma unroll
    for (int n = 0; n < 2; ++n)
      acc[m][n] = (f32x4){0.f, 0.f, 0.f, 0.f};

  auto stage = [&](int b, int k0) {
    #pragma unroll
    for (int j = 0; j < 2; ++j) {
      int chunk = tid + j * 256;
      int row = chunk >> 3;
      int t = chunk & 7;
      int col = (t ^ (row & 7)) * 8;   // inverse swizzle on global source
      GLOAD_LDS16(&A[(size_t)(mBase + row) * K + k0 + col],
                  &lds[b][0][(size_t)(wchunk + j * 256) * 8]);
      GLOAD_LDS16(&B[(size_t)(nBase + row) * K + k0 + col],
                  &lds[b][1][(size_t)(wchunk + j * 256) * 8]);
    }
  };

  const int kIters = kLen / 64;
  stage(0, kBase);
  __syncthreads();
  int buf = 0;
  for (int it = 0; it < kIters; ++it) {
    if (it + 1 < kIters) stage(buf ^ 1, kBase + (it + 1) * 64);
    short8 af[2][2], bfr[2][2];
    #pragma unroll
    for (int m = 0; m < 2; ++m)
      #pragma unroll
      for (int kk = 0; kk < 2; ++kk) {
        int row = wr + m * 16 + (lane & 15);
        int s = kk * 4 + (lane >> 4);
        af[m][kk] = *(const short8*)&lds[buf][0][row * 64 + ((s ^ (row & 7)) * 8)];
      }
    #pragma unroll
    for (int n = 0; n < 2; ++n)
      #pragma unroll
      for (int kk = 0; kk < 2; ++kk) {
        int row = wc + n * 16 + (lane & 15);
        int s = kk * 4 + (lane >> 4);
        bfr[n][kk] = *(const short8*)&lds[buf][1][row * 64 + ((s ^ (row & 7)) * 8)];
      }
    #pragma unroll
    for (int kk = 0; kk < 2; ++kk)
      #pragma unroll
      for (int m = 0; m < 2; ++m)
        #pragma unroll
        for (int n = 0; n < 2; ++n)
          acc[m][n] = __builtin_amdgcn_mfma_f32_16x16x32_bf16(
              af[m][kk], bfr[n][kk], acc[m][n], 0, 0, 0);
    __syncthreads();
    buf ^= 1;
  }

  if (OBF) {
    unsigned short* Cb = (unsigned short*)Cv;
    #pragma unroll
    for (int m = 0; m < 2; ++m) {
      int row0 = mBase + wr + m * 16 + (lane >> 4) * 4;
      #pragma unroll
      for (int n = 0; n < 2; ++n) {
        int col = nBase + wc + n * 16 + (lane & 15);
        #pragma unroll
        for (int r = 0; r < 4; ++r)
          Cb[(size_t)(row0 + r) * N + col] = f2bf(acc[m][n][r]);
      }
    }
  } else {
    float* Co = (float*)Cv + (SPLITK > 1 ? (size_t)bz * M * N : (size_t)0);
    #pragma unroll
    for (int m = 0; m < 2; ++m) {
      int row0 = mBase + wr + m * 16 + (lane >> 4) * 4;
      #pragma unroll
      for (int n = 0; n < 2; ++n) {
        int col = nBase + wc + n * 16 + (lane & 15);
        #pragma unroll
        for (int r = 0; r < 4; ++r)
          Co[(size_t)(row0 + r) * N + col] = acc[m][n][r];
      }
    }
  }
}

// out = partial0 + partial1 (split-K reduce), vectorized
__global__ __launch_bounds__(256) void reduce2(
    const float* __restrict__ P, float* __restrict__ out, int n4) {
  int i = blockIdx.x * 256 + threadIdx.x;
  if (i < n4) {
    f32x4 a = ((const f32x4*)P)[i];
    f32x4 b = ((const f32x4*)P)[i + n4];
    ((f32x4*)out)[i] = a + b;
  }
}

// ---------------------------------------------------------------------------
// causal depthwise conv (width 4) + silu, bf16 in (xz cols 0..2047) -> bf16 xi
// ---------------------------------------------------------------------------
__global__ __launch_bounds__(256) void conv_silu(
    const unsigned short* __restrict__ xz_bf, const float* __restrict__ cw,
    const float* __restrict__ cb, unsigned short* __restrict__ xi_b) {
  int d0 = threadIdx.x * 8;
  int l0 = blockIdx.x * 4;
  float wgt[8][4], bias[8];
  #pragma unroll
  for (int j = 0; j < 8; ++j) {
    float4 t = *(const float4*)&cw[(d0 + j) * 4];
    wgt[j][0] = t.x; wgt[j][1] = t.y; wgt[j][2] = t.z; wgt[j][3] = t.w;
  }
  *(float4*)(bias + 0) = *(const float4*)&cb[d0];
  *(float4*)(bias + 4) = *(const float4*)&cb[d0 + 4];

  short8 rows[7];
  #pragma unroll
  for (int r = 0; r < 7; ++r) {
    int ll = l0 - 3 + r;
    if (ll >= 0)
      rows[r] = *(const short8*)&xz_bf[(size_t)ll * 4096 + d0];
    else
      rows[r] = (short8){0, 0, 0, 0, 0, 0, 0, 0};
  }
  #pragma unroll
  for (int q = 0; q < 4; ++q) {
    short8 outv;
    #pragma unroll
    for (int j = 0; j < 8; ++j) {
      float acc = bias[j];
      #pragma unroll
      for (int k = 0; k < 4; ++k)
        acc = fmaf(bf2f((unsigned short)rows[q + k][j]), wgt[j][k], acc);
      float s = acc / (1.f + __expf(-acc));
      outv[j] = (short)f2bf(s);
    }
    *(short8*)&xi_b[(size_t)(l0 + q) * 2048 + d0] = outv;
  }
}

// ---------------------------------------------------------------------------
// x_dbl = xi @ x_proj_w^T  (M=1024, N=96, K=2048).  4 waves split K, LDS
// reduce.  cols 0..63 -> delta_raw (bf16), 64..79 -> Bm, 80..95 -> Cm (fp32)
// ---------------------------------------------------------------------------
__global__ __launch_bounds__(256) void xproj(
    const unsigned short* __restrict__ xi_b, const unsigned short* __restrict__ xw_b,
    unsigned short* __restrict__ xd_b, float* __restrict__ Bm, float* __restrict__ Cm) {
  __shared__ f32x4 red[4][64];
  int tid = threadIdx.x, lane = tid & 63, w = tid >> 6;
  int mt = blockIdx.x, nt = blockIdx.y;
  int arow = mt * 16 + (lane & 15);
  int brow = nt * 16 + (lane & 15);
  int kg = (lane >> 4) * 8;
  f32x4 acc = (f32x4){0.f, 0.f, 0.f, 0.f};
  for (int k0 = w * 512; k0 < (w + 1) * 512; k0 += 32) {
    short8 a = *(const short8*)&xi_b[(size_t)arow * 2048 + k0 + kg];
    short8 b = *(const short8*)&xw_b[(size_t)brow * 2048 + k0 + kg];
    acc = __builtin_amdgcn_mfma_f32_16x16x32_bf16(a, b, acc, 0, 0, 0);
  }
  red[w][lane] = acc;
  __syncthreads();
  if (w == 0) {
    acc = red[0][lane];
    acc += red[1][lane];
    acc += red[2][lane];
    acc += red[3][lane];
    int ocol = nt * 16 + (lane & 15);
    #pragma unroll
    for (int r = 0; r < 4; ++r) {
      int row = mt * 16 + (lane >> 4) * 4 + r;
      float v = acc[r];
      if (ocol < 64)      xd_b[row * 64 + ocol] = f2bf(v);
      else if (ocol < 80) Bm[row * 16 + (ocol - 64)] = v;
      else                Cm[row * 16 + (ocol - 80)] = v;
    }
  }
}

// ---------------------------------------------------------------------------
// Fused dtproj + chunked selective scan, ONE cooperative kernel.
// Grid 1024 blocks x 64 threads (1 wave).  Block (dblk = bid&31, c = bid>>5)
// owns channels d = dblk*64+lane, chunk c (32 timesteps).
// Phase A: delta tile via MFMA (xd @ dtw^T + bias, softplus) -> LDS.
// Phase B: local scan; u/B cached in LDS; write P (decay prod) & S (state).
// grid.sync
// Phase D: 32768 threads chain the 32 chunks -> SIn (incoming states).
// grid.sync
// Phase E: replay from LDS with incoming state; y = C.s + u*D, *silu(z).
// ---------------------------------------------------------------------------
__global__ __launch_bounds__(64) void scan_fused(
    const unsigned short* __restrict__ xd, const unsigned short* __restrict__ dtw,
    const float* __restrict__ dtb, const unsigned short* __restrict__ xi,
    const float* __restrict__ BmG, const float* __restrict__ CmG,
    const float* __restrict__ Alog, const float* __restrict__ Dv,
    const unsigned short* __restrict__ xz, float* __restrict__ P,
    float* __restrict__ S, float* __restrict__ SIn,
    unsigned short* __restrict__ y_b) {
  __shared__ float ldsD[32 * 64];          // delta tile [t][d]  8KB
  __shared__ unsigned short ldsU[32 * 64]; // u tile     [t][d]  4KB
  __shared__ float ldsB[32 * 16];          // B tile     [t][n]  2KB
  __shared__ float ldsC[32 * 16];          // C tile     [t][n]  2KB
  const int bid = blockIdx.x;
  const int dblk = bid & 31, c = bid >> 5;
  const int lane = threadIdx.x;
  const int d = dblk * 64 + lane;

  // ---- stage B/C tiles (rows c*32..c*32+31, 16 n each = 512 floats) ----
  #pragma unroll
  for (int i = 0; i < 8; ++i) {
    ldsB[lane + i * 64] = BmG[c * 512 + lane + i * 64];
    ldsC[lane + i * 64] = CmG[c * 512 + lane + i * 64];
  }

  // ---- Phase A: dtproj MFMA -> ldsD ----
  {
    short8 afr[2][2], bfr[4][2];
    #pragma unroll
    for (int lt = 0; lt < 2; ++lt)
      #pragma unroll
      for (int kk = 0; kk < 2; ++kk)
        afr[lt][kk] = *(const short8*)
            &xd[(size_t)(c * 32 + lt * 16 + (lane & 15)) * 64 + kk * 32 + (lane >> 4) * 8];
    #pragma unroll
    for (int dt = 0; dt < 4; ++dt)
      #pragma unroll
      for (int kk = 0; kk < 2; ++kk)
        bfr[dt][kk] = *(const short8*)
            &dtw[(size_t)(dblk * 64 + dt * 16 + (lane & 15)) * 64 + kk * 32 + (lane >> 4) * 8];
    f32x4 acc[2][4];
    #pragma unroll
    for (int lt = 0; lt < 2; ++lt)
      #pragma unroll
      for (int dt = 0; dt < 4; ++dt)
        acc[lt][dt] = (f32x4){0.f, 0.f, 0.f, 0.f};
    #pragma unroll
    for (int kk = 0; kk < 2; ++kk)
      #pragma unroll
      for (int lt = 0; lt < 2; ++lt)
        #pragma unroll
        for (int dt = 0; dt < 4; ++dt)
          acc[lt][dt] = __builtin_amdgcn_mfma_f32_16x16x32_bf16(
              afr[lt][kk], bfr[dt][kk], acc[lt][dt], 0, 0, 0);
    #pragma unroll
    for (int dt = 0; dt < 4; ++dt) {
      int dl_ = dt * 16 + (lane & 15);
      float bias = dtb[dblk * 64 + dl_];
      #pragma unroll
      for (int lt = 0; lt < 2; ++lt) {
        #pragma unroll
        for (int r = 0; r < 4; ++r) {
          int ll = lt * 16 + (lane >> 4) * 4 + r;
          float v = acc[lt][dt][r] + bias;
          float sp = (v > 20.f) ? v : log1pf(__expf(v));
          ldsD[ll * 64 + dl_] = sp;
        }
      }
    }
  }
  // single wave per block: LDS RAW ordering handled by waitcnt, no barrier.

  // ---- Phase B: local chunk scan ----
  float a[16], p[16], s[16];
  #pragma unroll
  for (int n = 0; n < 16; ++n) {
    a[n] = -__expf(Alog[d * 16 + n]);
    p[n] = 1.f; s[n] = 0.f;
  }
  for (int t = 0; t < 32; ++t) {
    int l = c * 32 + t;
    float dl = ldsD[t * 64 + lane];
    unsigned short ub = xi[(size_t)l * 2048 + d];
    ldsU[t * 64 + lane] = ub;
    float u = bf2f(ub);
    float du = dl * u;
    float bv[16];
    *(float4*)(bv + 0)  = *(const float4*)&ldsB[t * 16 + 0];
    *(float4*)(bv + 4)  = *(const float4*)&ldsB[t * 16 + 4];
    *(float4*)(bv + 8)  = *(const float4*)&ldsB[t * 16 + 8];
    *(float4*)(bv + 12) = *(const float4*)&ldsB[t * 16 + 12];
    #pragma unroll
    for (int n = 0; n < 16; ++n) {
      float dA = __expf(dl * a[n]);
      s[n] = fmaf(dA, s[n], du * bv[n]);
      p[n] *= dA;
    }
  }
  #pragma unroll
  for (int n = 0; n < 16; ++n) {
    P[(size_t)(c * 16 + n) * 2048 + d] = p[n];
    S[(size_t)(c * 16 + n) * 2048 + d] = s[n];
  }

  __threadfence();
  cg::this_grid().sync();

  // ---- Phase D: chunk-combine (first 32768 threads) ----
  int gid = bid * 64 + lane;
  if (gid < 32768) {
    float run = 0.f;
    #pragma unroll 4
    for (int cc = 0; cc < 32; ++cc) {
      SIn[cc * 32768 + gid] = run;
      run = fmaf(P[cc * 32768 + gid], run, S[cc * 32768 + gid]);
    }
  }

  __threadfence();
  cg::this_grid().sync();

  // ---- Phase E: replay with incoming state, emit gated y (bf16) ----
  #pragma unroll
  for (int n = 0; n < 16; ++n)
    s[n] = SIn[c * 32768 + n * 2048 + d];
  float Dd = Dv[d];
  for (int t = 0; t < 32; ++t) {
    int l = c * 32 + t;
    float dl = ldsD[t * 64 + lane];
    float u  = bf2f(ldsU[t * 64 + lane]);
    float du = dl * u;
    float bv[16], cv[16];
    *(float4*)(bv + 0)  = *(const float4*)&ldsB[t * 16 + 0];
    *(float4*)(bv + 4)  = *(const float4*)&ldsB[t * 16 + 4];
    *(float4*)(bv + 8)  = *(const float4*)&ldsB[t * 16 + 8];
    *(float4*)(bv + 12) = *(const float4*)&ldsB[t * 16 + 12];
    *(float4*)(cv + 0)  = *(const float4*)&ldsC[t * 16 + 0];
    *(float4*)(cv + 4)  = *(const float4*)&ldsC[t * 16 + 4];
    *(float4*)(cv + 8)  = *(const float4*)&ldsC[t * 16 + 8];
    *(float4*)(cv + 12) = *(const float4*)&ldsC[t * 16 + 12];
    float y = 0.f;
    #pragma unroll
    for (int n = 0; n < 16; ++n) {
      float dA = __expf(dl * a[n]);
      s[n] = fmaf(dA, s[n], du * bv[n]);
      y = fmaf(s[n], cv[n], y);
    }
    y = fmaf(u, Dd, y);
    float zz = bf2f(xz[(size_t)l * 4096 + 2048 + d]);
    float sig = 1.f / (1.f + __expf(-zz));
    y *= zz * sig;
    y_b[(size_t)l * 2048 + d] = f2bf(y);
  }
}

// ---------------------------------------------------------------------------
extern "C" void kernel_launch(void* const* d_in, const int* in_sizes, int n_in,
                              void* d_out, int out_size, void* d_ws, size_t ws_size,
                              hipStream_t stream) {
  const float* x      = (const float*)d_in[0];
  const float* Win    = (const float*)d_in[1];
  const float* convw  = (const float*)d_in[2];
  const float* convb  = (const float*)d_in[3];
  const float* xprojw = (const float*)d_in[4];
  const float* dtw    = (const float*)d_in[5];
  const float* dtb    = (const float*)d_in[6];
  const float* Alog   = (const float*)d_in[7];
  const float* Dv     = (const float*)d_in[8];
  const float* Wout   = (const float*)d_in[9];
  float* out = (float*)d_out;

  char* ws = (char*)d_ws;
  size_t off = 0;
  auto alloc = [&](size_t bytes) -> void* {
    void* p = ws + off;
    off = (off + bytes + 255) & ~(size_t)255;
    return p;
  };
  unsigned short* x_bf    = (unsigned short*)alloc((size_t)1024 * 1024 * 2);
  unsigned short* Win_bf  = (unsigned short*)alloc((size_t)4096 * 1024 * 2);
  unsigned short* Wout_bf = (unsigned short*)alloc((size_t)1024 * 2048 * 2);
  unsigned short* xw_bf   = (unsigned short*)alloc((size_t)96 * 2048 * 2);
  unsigned short* dtw_bf  = (unsigned short*)alloc((size_t)2048 * 64 * 2);
  unsigned short* xz_bf   = (unsigned short*)alloc((size_t)1024 * 4096 * 2);
  unsigned short* xi_bf   = (unsigned short*)alloc((size_t)1024 * 2048 * 2);
  unsigned short* xd_bf   = (unsigned short*)alloc((size_t)1024 * 64 * 2);
  float* Bm               = (float*)alloc((size_t)1024 * 16 * 4);
  float* Cm               = (float*)alloc((size_t)1024 * 16 * 4);
  float* P                = (float*)alloc((size_t)32 * 16 * 2048 * 4);  // 4MB
  float* S                = (float*)alloc((size_t)32 * 16 * 2048 * 4);  // 4MB, contiguous after P
  float* SIn              = (float*)alloc((size_t)32 * 16 * 2048 * 4);
  unsigned short* y_bf    = (unsigned short*)alloc((size_t)1024 * 2048 * 2);
  // P,S dead after scan -> reused as split-K partials (contiguous 8MB).

  convert_all<<<dim3(512, 5), 256, 0, stream>>>(
      x, x_bf, 1024 * 1024,
      Win, Win_bf, 4096 * 1024,
      Wout, Wout_bf, 1024 * 2048,
      xprojw, xw_bf, 96 * 2048,
      dtw, dtw_bf, 2048 * 64);
  gemm64<1, 1><<<dim3(64, 16), 256, 0, stream>>>(x_bf, Win_bf, xz_bf, 1024, 4096, 1024);
  conv_silu<<<dim3(256), 256, 0, stream>>>(xz_bf, convw, convb, xi_bf);
  xproj<<<dim3(64, 6), 256, 0, stream>>>(xi_bf, xw_bf, xd_bf, Bm, Cm);

  {
    void* args[] = {
      (void*)&xd_bf, (void*)&dtw_bf, (void*)&dtb, (void*)&xi_bf,
      (void*)&Bm, (void*)&Cm, (void*)&Alog, (void*)&Dv,
      (void*)&xz_bf, (void*)&P, (void*)&S, (void*)&SIn, (void*)&y_bf
    };
    hipLaunchCooperativeKernel((const void*)scan_fused, dim3(1024), dim3(64),
                               args, 0, stream);
  }

  gemm64<2, 0><<<dim3(16, 16, 2), 256, 0, stream>>>(y_bf, Wout_bf, P, 1024, 1024, 2048);
  reduce2<<<dim3(1024), 256, 0, stream>>>(P, out, 262144);
}

// Round 5
// 129.990 us; speedup vs baseline: 2.7697x; 2.7697x over previous
//
#include <hip/hip_runtime.h>
#include <hip/hip_bf16.h>
#include <cstdint>
#include <cstddef>

// ---------------------------------------------------------------------------
// Mamba block forward, MI355X (gfx950).  Round 5.
// Changes vs round 4: cooperative scan REVERTED (grid.sync cost ~270us on
// multi-XCD gfx950).  vs round 3:
//  - gemm64 staging templated per operand: fp32 operands reg-loaded early,
//    cvt+ds_write after MFMA (T14 overlap); bf16 operands via global_load_lds.
//    in_proj consumes x/W fp32 directly; out_proj consumes Wout fp32 directly.
//    convert_all shrinks to xw+dtw (0.65 MB).
//  - dtproj fused into scan_p1 AND scan_p3 (per-block MFMA delta tile in LDS,
//    recomputed in p3; no global delta buffer, no dtproj launch).
//  - scan tiles (xi, z, B, C) staged into LDS with 16B loads.
// ---------------------------------------------------------------------------

typedef __attribute__((ext_vector_type(4))) float f32x4;
typedef __attribute__((ext_vector_type(8))) short short8;

#define GLOAD_LDS16(g, l)                                                      \
  __builtin_amdgcn_global_load_lds(                                            \
      (const __attribute__((address_space(1))) void*)(g),                      \
      (__attribute__((address_space(3))) void*)(l), 16, 0, 0)

__device__ __forceinline__ unsigned short f2bf(float f) {
  union { float f; unsigned u; } v; v.f = f;
  unsigned u = v.u;
  unsigned r = (u + 0x7FFFu + ((u >> 16) & 1u)) >> 16;  // round-to-nearest-even
  return (unsigned short)r;
}
__device__ __forceinline__ float bf2f(unsigned short u) {
  union { unsigned u; float f; } v; v.u = ((unsigned)u) << 16;
  return v.f;
}

// ---------------------------------------------------------------------------
// small fp32->bf16 convert: two arrays (xw, dtw)
// ---------------------------------------------------------------------------
__global__ __launch_bounds__(256) void convert2(
    const float* __restrict__ a0, unsigned short* __restrict__ o0, int n0,
    const float* __restrict__ a1, unsigned short* __restrict__ o1, int n1) {
  int i = blockIdx.x * 256 + threadIdx.x;
  int t0 = n0 >> 2, t1 = n1 >> 2;
  const float* a; unsigned short* o;
  if (i < t0) {
    a = a0; o = o0;
  } else if (i < t0 + t1) {
    i -= t0; a = a1; o = o1;
  } else return;
  float4 v = ((const float4*)a)[i];
  uint2 p;
  p.x = (unsigned)f2bf(v.x) | ((unsigned)f2bf(v.y) << 16);
  p.y = (unsigned)f2bf(v.z) | ((unsigned)f2bf(v.w) << 16);
  ((uint2*)o)[i] = p;
}

// ---------------------------------------------------------------------------
// 64x64-tile bf16-MFMA GEMM, C = A @ B^T.  Per-operand staging:
//   *F32=1: operand is fp32 in global; reg-load (issued before MFMA), cvt to
//           bf16, swizzled ds_write after MFMA (single barrier per iter).
//   *F32=0: operand is bf16; global_load_lds 16B with inverse-swizzled source.
// XOR swizzle on 16B k-slots: phys = s ^ (row&7).  Double-buffered LDS.
// XCD-chunked bijective block swizzle (needs gridDim.x % 8 == 0).
// OBF: write C bf16.  SPLITK>1: partials at C + z*M*N (fp32).
// ---------------------------------------------------------------------------
template <int AF32, int BF32, int SPLITK, int OBF>
__global__ __launch_bounds__(256) void gemm64(
    const void* __restrict__ Av, const void* __restrict__ Bv,
    void* __restrict__ Cv, int M, int N, int K) {
  __shared__ unsigned short lds[2][2][64 * 64];  // 32KB
  const int tid  = threadIdx.x;
  const int lane = tid & 63;
  const int w    = tid >> 6;

  // bijective XCD-chunked swizzle
  const int nx = gridDim.x, ny = gridDim.y;
  int li = (blockIdx.z * ny + blockIdx.y) * nx + blockIdx.x;
  int xcd = li & 7, idx = li >> 3;
  int by = idx % ny;
  int r_ = idx / ny;
  int slab = nx >> 3;
  int bx = xcd * slab + (r_ % slab);
  int bz = r_ / slab;

  const int mBase = by * 64;
  const int nBase = bx * 64;
  const int kLen  = K / SPLITK;
  const int kBase = (SPLITK > 1) ? bz * kLen : 0;
  const int wr = (w >> 1) * 32;
  const int wc = (w & 1) * 32;
  const int wchunk = tid & 192;  // wave-uniform chunk base for gload_lds

  // fp32-staging coords: thread covers row srow, 16 k at sseg (2 slots)
  const int srow  = tid >> 2;
  const int sseg  = (tid & 3) * 16;
  const int sslot = (tid & 3) * 2;

  float4 ra[4], rb[4];

  auto loadA_f32 = [&](int k0) {
    const float* Af = (const float*)Av;
    #pragma unroll
    for (int i = 0; i < 4; ++i)
      ra[i] = *(const float4*)&Af[(size_t)(mBase + srow) * K + k0 + sseg + i * 4];
  };
  auto loadB_f32 = [&](int k0) {
    const float* Bf = (const float*)Bv;
    #pragma unroll
    for (int i = 0; i < 4; ++i)
      rb[i] = *(const float4*)&Bf[(size_t)(nBase + srow) * K + k0 + sseg + i * 4];
  };
  auto writeA_f32 = [&](int b) {
    unsigned short tmp[16];
    #pragma unroll
    for (int i = 0; i < 4; ++i) {
      tmp[i * 4 + 0] = f2bf(ra[i].x); tmp[i * 4 + 1] = f2bf(ra[i].y);
      tmp[i * 4 + 2] = f2bf(ra[i].z); tmp[i * 4 + 3] = f2bf(ra[i].w);
    }
    *(int4*)&lds[b][0][srow * 64 + ((sslot ^ (srow & 7)) * 8)] = *(int4*)&tmp[0];
    *(int4*)&lds[b][0][srow * 64 + (((sslot + 1) ^ (srow & 7)) * 8)] = *(int4*)&tmp[8];
  };
  auto writeB_f32 = [&](int b) {
    unsigned short tmp[16];
    #pragma unroll
    for (int i = 0; i < 4; ++i) {
      tmp[i * 4 + 0] = f2bf(rb[i].x); tmp[i * 4 + 1] = f2bf(rb[i].y);
      tmp[i * 4 + 2] = f2bf(rb[i].z); tmp[i * 4 + 3] = f2bf(rb[i].w);
    }
    *(int4*)&lds[b][1][srow * 64 + ((sslot ^ (srow & 7)) * 8)] = *(int4*)&tmp[0];
    *(int4*)&lds[b][1][srow * 64 + (((sslot + 1) ^ (srow & 7)) * 8)] = *(int4*)&tmp[8];
  };
  auto gloadA = [&](int b, int k0) {
    const unsigned short* Ab = (const unsigned short*)Av;
    #pragma unroll
    for (int j = 0; j < 2; ++j) {
      int chunk = tid + j * 256;
      int row = chunk >> 3, t = chunk & 7;
      int col = (t ^ (row & 7)) * 8;   // inverse swizzle on global source
      GLOAD_LDS16(&Ab[(size_t)(mBase + row) * K + k0 + col],
                  &lds[b][0][(size_t)(wchunk + j * 256) * 8]);
    }
  };
  auto gloadB = [&](int b, int k0) {
    const unsigned short* Bb = (const unsigned short*)Bv;
    #pragma unroll
    for (int j = 0; j < 2; ++j) {
      int chunk = tid + j * 256;
      int row = chunk >> 3, t = chunk & 7;
      int col = (t ^ (row & 7)) * 8;
      GLOAD_LDS16(&Bb[(size_t)(nBase + row) * K + k0 + col],
                  &lds[b][1][(size_t)(wchunk + j * 256) * 8]);
    }
  };

  f32x4 acc[2][2];
  #pragma unroll
  for (int m = 0; m < 2; ++m)
    #pragma unroll
    for (int n = 0; n < 2; ++n)
      acc[m][n] = (f32x4){0.f, 0.f, 0.f, 0.f};

  const int kIters = kLen / 64;
  // prologue: stage tile 0
  if (AF32) { loadA_f32(kBase); writeA_f32(0); } else gloadA(0, kBase);
  if (BF32) { loadB_f32(kBase); writeB_f32(0); } else gloadB(0, kBase);
  __syncthreads();

  int buf = 0;
  for (int it = 0; it < kIters; ++it) {
    bool pre = (it + 1 < kIters);
    int kn = kBase + (it + 1) * 64;
    if (pre) {  // issue loads early: latency hides under MFMA below
      if (AF32) loadA_f32(kn); else gloadA(buf ^ 1, kn);
      if (BF32) loadB_f32(kn); else gloadB(buf ^ 1, kn);
    }
    short8 af[2][2], bfr[2][2];
    #pragma unroll
    for (int m = 0; m < 2; ++m)
      #pragma unroll
      for (int kk = 0; kk < 2; ++kk) {
        int row = wr + m * 16 + (lane & 15);
        int s = kk * 4 + (lane >> 4);
        af[m][kk] = *(const short8*)&lds[buf][0][row * 64 + ((s ^ (row & 7)) * 8)];
      }
    #pragma unroll
    for (int n = 0; n < 2; ++n)
      #pragma unroll
      for (int kk = 0; kk < 2; ++kk) {
        int row = wc + n * 16 + (lane & 15);
        int s = kk * 4 + (lane >> 4);
        bfr[n][kk] = *(const short8*)&lds[buf][1][row * 64 + ((s ^ (row & 7)) * 8)];
      }
    #pragma unroll
    for (int kk = 0; kk < 2; ++kk)
      #pragma unroll
      for (int m = 0; m < 2; ++m)
        #pragma unroll
        for (int n = 0; n < 2; ++n)
          acc[m][n] = __builtin_amdgcn_mfma_f32_16x16x32_bf16(
              af[m][kk], bfr[n][kk], acc[m][n], 0, 0, 0);
    if (pre) {  // write the prefetched tile into the OTHER buffer (safe)
      if (AF32) writeA_f32(buf ^ 1);
      if (BF32) writeB_f32(buf ^ 1);
    }
    __syncthreads();  // drains vmcnt (gload_lds) + lgkmcnt (ds_write)
    buf ^= 1;
  }

  if (OBF) {
    unsigned short* Cb = (unsigned short*)Cv;
    #pragma unroll
    for (int m = 0; m < 2; ++m) {
      int row0 = mBase + wr + m * 16 + (lane >> 4) * 4;
      #pragma unroll
      for (int n = 0; n < 2; ++n) {
        int col = nBase + wc + n * 16 + (lane & 15);
        #pragma unroll
        for (int r = 0; r < 4; ++r)
          Cb[(size_t)(row0 + r) * N + col] = f2bf(acc[m][n][r]);
      }
    }
  } else {
    float* Co = (float*)Cv + (SPLITK > 1 ? (size_t)bz * M * N : (size_t)0);
    #pragma unroll
    for (int m = 0; m < 2; ++m) {
      int row0 = mBase + wr + m * 16 + (lane >> 4) * 4;
      #pragma unroll
      for (int n = 0; n < 2; ++n) {
        int col = nBase + wc + n * 16 + (lane & 15);
        #pragma unroll
        for (int r = 0; r < 4; ++r)
          Co[(size_t)(row0 + r) * N + col] = acc[m][n][r];
      }
    }
  }
}

// out = partial0 + partial1 (split-K reduce), vectorized
__global__ __launch_bounds__(256) void reduce2(
    const float* __restrict__ P, float* __restrict__ out, int n4) {
  int i = blockIdx.x * 256 + threadIdx.x;
  if (i < n4) {
    f32x4 a = ((const f32x4*)P)[i];
    f32x4 b = ((const f32x4*)P)[i + n4];
    ((f32x4*)out)[i] = a + b;
  }
}

// ---------------------------------------------------------------------------
// causal depthwise conv (width 4) + silu, bf16 in (xz cols 0..2047) -> bf16 xi
// ---------------------------------------------------------------------------
__global__ __launch_bounds__(256) void conv_silu(
    const unsigned short* __restrict__ xz_bf, const float* __restrict__ cw,
    const float* __restrict__ cb, unsigned short* __restrict__ xi_b) {
  int d0 = threadIdx.x * 8;
  int l0 = blockIdx.x * 4;
  float wgt[8][4], bias[8];
  #pragma unroll
  for (int j = 0; j < 8; ++j) {
    float4 t = *(const float4*)&cw[(d0 + j) * 4];
    wgt[j][0] = t.x; wgt[j][1] = t.y; wgt[j][2] = t.z; wgt[j][3] = t.w;
  }
  *(float4*)(bias + 0) = *(const float4*)&cb[d0];
  *(float4*)(bias + 4) = *(const float4*)&cb[d0 + 4];

  short8 rows[7];
  #pragma unroll
  for (int r = 0; r < 7; ++r) {
    int ll = l0 - 3 + r;
    if (ll >= 0)
      rows[r] = *(const short8*)&xz_bf[(size_t)ll * 4096 + d0];
    else
      rows[r] = (short8){0, 0, 0, 0, 0, 0, 0, 0};
  }
  #pragma unroll
  for (int q = 0; q < 4; ++q) {
    short8 outv;
    #pragma unroll
    for (int j = 0; j < 8; ++j) {
      float acc = bias[j];
      #pragma unroll
      for (int k = 0; k < 4; ++k)
        acc = fmaf(bf2f((unsigned short)rows[q + k][j]), wgt[j][k], acc);
      float s = acc / (1.f + __expf(-acc));
      outv[j] = (short)f2bf(s);
    }
    *(short8*)&xi_b[(size_t)(l0 + q) * 2048 + d0] = outv;
  }
}

// ---------------------------------------------------------------------------
// x_dbl = xi @ x_proj_w^T  (M=1024, N=96, K=2048).  4 waves split K, LDS
// reduce.  cols 0..63 -> delta_raw (bf16), 64..79 -> Bm, 80..95 -> Cm (fp32)
// ---------------------------------------------------------------------------
__global__ __launch_bounds__(256) void xproj(
    const unsigned short* __restrict__ xi_b, const unsigned short* __restrict__ xw_b,
    unsigned short* __restrict__ xd_b, float* __restrict__ Bm, float* __restrict__ Cm) {
  __shared__ f32x4 red[4][64];
  int tid = threadIdx.x, lane = tid & 63, w = tid >> 6;
  int mt = blockIdx.x, nt = blockIdx.y;
  int arow = mt * 16 + (lane & 15);
  int brow = nt * 16 + (lane & 15);
  int kg = (lane >> 4) * 8;
  f32x4 acc = (f32x4){0.f, 0.f, 0.f, 0.f};
  for (int k0 = w * 512; k0 < (w + 1) * 512; k0 += 32) {
    short8 a = *(const short8*)&xi_b[(size_t)arow * 2048 + k0 + kg];
    short8 b = *(const short8*)&xw_b[(size_t)brow * 2048 + k0 + kg];
    acc = __builtin_amdgcn_mfma_f32_16x16x32_bf16(a, b, acc, 0, 0, 0);
  }
  red[w][lane] = acc;
  __syncthreads();
  if (w == 0) {
    acc = red[0][lane];
    acc += red[1][lane];
    acc += red[2][lane];
    acc += red[3][lane];
    int ocol = nt * 16 + (lane & 15);
    #pragma unroll
    for (int r = 0; r < 4; ++r) {
      int row = mt * 16 + (lane >> 4) * 4 + r;
      float v = acc[r];
      if (ocol < 64)      xd_b[row * 64 + ocol] = f2bf(v);
      else if (ocol < 80) Bm[row * 16 + (ocol - 64)] = v;
      else                Cm[row * 16 + (ocol - 80)] = v;
    }
  }
}

// ---------------------------------------------------------------------------
// dtproj tile (MFMA) -> ldsD.  Shared by scan_p1 / scan_p3.  One wave.
// delta[l][d] tile for l in [c*32, c*32+32), d in [dblk*64, dblk*64+64).
// ---------------------------------------------------------------------------
__device__ __forceinline__ void dt_tile(
    const unsigned short* __restrict__ xd, const unsigned short* __restrict__ dtw,
    const float* __restrict__ dtb, int c, int dblk, int lane,
    float* __restrict__ ldsD) {
  short8 afr[2][2], bfr4[4][2];
  #pragma unroll
  for (int lt = 0; lt < 2; ++lt)
    #pragma unroll
    for (int kk = 0; kk < 2; ++kk)
      afr[lt][kk] = *(const short8*)
          &xd[(size_t)(c * 32 + lt * 16 + (lane & 15)) * 64 + kk * 32 + (lane >> 4) * 8];
  #pragma unroll
  for (int dt = 0; dt < 4; ++dt)
    #pragma unroll
    for (int kk = 0; kk < 2; ++kk)
      bfr4[dt][kk] = *(const short8*)
          &dtw[(size_t)(dblk * 64 + dt * 16 + (lane & 15)) * 64 + kk * 32 + (lane >> 4) * 8];
  f32x4 acc[2][4];
  #pragma unroll
  for (int lt = 0; lt < 2; ++lt)
    #pragma unroll
    for (int dt = 0; dt < 4; ++dt)
      acc[lt][dt] = (f32x4){0.f, 0.f, 0.f, 0.f};
  #pragma unroll
  for (int kk = 0; kk < 2; ++kk)
    #pragma unroll
    for (int lt = 0; lt < 2; ++lt)
      #pragma unroll
      for (int dt = 0; dt < 4; ++dt)
        acc[lt][dt] = __builtin_amdgcn_mfma_f32_16x16x32_bf16(
            afr[lt][kk], bfr4[dt][kk], acc[lt][dt], 0, 0, 0);
  #pragma unroll
  for (int dt = 0; dt < 4; ++dt) {
    int dl_ = dt * 16 + (lane & 15);
    float bias = dtb[dblk * 64 + dl_];
    #pragma unroll
    for (int lt = 0; lt < 2; ++lt) {
      #pragma unroll
      for (int r = 0; r < 4; ++r) {
        int ll = lt * 16 + (lane >> 4) * 4 + r;
        float v = acc[lt][dt][r] + bias;
        float sp = (v > 20.f) ? v : log1pf(__expf(v));  // softplus
        ldsD[ll * 64 + dl_] = sp;
      }
    }
  }
}

// ---------------------------------------------------------------------------
// Chunked selective scan, 32 chunks x 32 steps.  Block (dblk, c) = 1 wave.
// p1: dtproj tile + local scan -> P (decay products), S (local states).
// ---------------------------------------------------------------------------
__global__ __launch_bounds__(64) void scan_p1(
    const unsigned short* __restrict__ xd, const unsigned short* __restrict__ dtw,
    const float* __restrict__ dtb, const unsigned short* __restrict__ xi,
    const float* __restrict__ BmG, const float* __restrict__ Alog,
    float* __restrict__ P, float* __restrict__ S) {
  __shared__ float ldsD[32 * 64];          // delta [t][d]  8KB
  __shared__ unsigned short ldsU[32 * 64]; // u     [t][d]  4KB
  __shared__ float ldsB[32 * 16];          // B     [t][n]  2KB
  const int dblk = blockIdx.x, c = blockIdx.y;
  const int lane = threadIdx.x;
  const int d = dblk * 64 + lane;

  #pragma unroll
  for (int i = 0; i < 8; ++i)
    ldsB[lane + i * 64] = BmG[c * 512 + lane + i * 64];
  #pragma unroll
  for (int i = 0; i < 4; ++i) {   // u tile, 16B chunks
    int chunk = lane + i * 64;
    int row = chunk >> 3, c8 = chunk & 7;
    *(int4*)&ldsU[row * 64 + c8 * 8] =
        *(const int4*)&xi[(size_t)(c * 32 + row) * 2048 + dblk * 64 + c8 * 8];
  }
  dt_tile(xd, dtw, dtb, c, dblk, lane, ldsD);
  __syncthreads();

  float a[16], p[16], s[16];
  #pragma unroll
  for (int n = 0; n < 16; ++n) {
    a[n] = -__expf(Alog[d * 16 + n]);
    p[n] = 1.f; s[n] = 0.f;
  }
  for (int t = 0; t < 32; ++t) {
    float dl = ldsD[t * 64 + lane];
    float u  = bf2f(ldsU[t * 64 + lane]);
    float du = dl * u;
    float bv[16];
    *(float4*)(bv + 0)  = *(const float4*)&ldsB[t * 16 + 0];
    *(float4*)(bv + 4)  = *(const float4*)&ldsB[t * 16 + 4];
    *(float4*)(bv + 8)  = *(const float4*)&ldsB[t * 16 + 8];
    *(float4*)(bv + 12) = *(const float4*)&ldsB[t * 16 + 12];
    #pragma unroll
    for (int n = 0; n < 16; ++n) {
      float dA = __expf(dl * a[n]);
      s[n] = fmaf(dA, s[n], du * bv[n]);
      p[n] *= dA;
    }
  }
  #pragma unroll
  for (int n = 0; n < 16; ++n) {
    P[(size_t)(c * 16 + n) * 2048 + d] = p[n];
    S[(size_t)(c * 16 + n) * 2048 + d] = s[n];
  }
}

__global__ __launch_bounds__(256) void scan_p2(
    const float* __restrict__ P, const float* __restrict__ S,
    float* __restrict__ SIn) {
  int idx = blockIdx.x * 256 + threadIdx.x;  // 0..32767 = n*2048+d
  float sin_ = 0.f;
  #pragma unroll 4
  for (int c = 0; c < 32; ++c) {
    SIn[c * 32768 + idx] = sin_;
    sin_ = fmaf(P[c * 32768 + idx], sin_, S[c * 32768 + idx]);
  }
}

__global__ __launch_bounds__(64) void scan_p3(
    const unsigned short* __restrict__ xd, const unsigned short* __restrict__ dtw,
    const float* __restrict__ dtb, const unsigned short* __restrict__ xi,
    const float* __restrict__ BmG, const float* __restrict__ CmG,
    const float* __restrict__ Alog, const float* __restrict__ Dv,
    const float* __restrict__ SIn, const unsigned short* __restrict__ xz,
    unsigned short* __restrict__ y_b) {
  __shared__ float ldsD[32 * 64];
  __shared__ unsigned short ldsU[32 * 64];
  __shared__ unsigned short ldsZ[32 * 64];
  __shared__ float ldsB[32 * 16];
  __shared__ float ldsC[32 * 16];
  const int dblk = blockIdx.x, c = blockIdx.y;
  const int lane = threadIdx.x;
  const int d = dblk * 64 + lane;

  #pragma unroll
  for (int i = 0; i < 8; ++i) {
    ldsB[lane + i * 64] = BmG[c * 512 + lane + i * 64];
    ldsC[lane + i * 64] = CmG[c * 512 + lane + i * 64];
  }
  #pragma unroll
  for (int i = 0; i < 4; ++i) {
    int chunk = lane + i * 64;
    int row = chunk >> 3, c8 = chunk & 7;
    *(int4*)&ldsU[row * 64 + c8 * 8] =
        *(const int4*)&xi[(size_t)(c * 32 + row) * 2048 + dblk * 64 + c8 * 8];
    *(int4*)&ldsZ[row * 64 + c8 * 8] =
        *(const int4*)&xz[(size_t)(c * 32 + row) * 4096 + 2048 + dblk * 64 + c8 * 8];
  }
  dt_tile(xd, dtw, dtb, c, dblk, lane, ldsD);
  __syncthreads();

  float a[16], s[16];
  #pragma unroll
  for (int n = 0; n < 16; ++n) {
    a[n] = -__expf(Alog[d * 16 + n]);
    s[n] = SIn[c * 32768 + n * 2048 + d];
  }
  float Dd = Dv[d];
  for (int t = 0; t < 32; ++t) {
    float dl = ldsD[t * 64 + lane];
    float u  = bf2f(ldsU[t * 64 + lane]);
    float du = dl * u;
    float bv[16], cv[16];
    *(float4*)(bv + 0)  = *(const float4*)&ldsB[t * 16 + 0];
    *(float4*)(bv + 4)  = *(const float4*)&ldsB[t * 16 + 4];
    *(float4*)(bv + 8)  = *(const float4*)&ldsB[t * 16 + 8];
    *(float4*)(bv + 12) = *(const float4*)&ldsB[t * 16 + 12];
    *(float4*)(cv + 0)  = *(const float4*)&ldsC[t * 16 + 0];
    *(float4*)(cv + 4)  = *(const float4*)&ldsC[t * 16 + 4];
    *(float4*)(cv + 8)  = *(const float4*)&ldsC[t * 16 + 8];
    *(float4*)(cv + 12) = *(const float4*)&ldsC[t * 16 + 12];
    float y = 0.f;
    #pragma unroll
    for (int n = 0; n < 16; ++n) {
      float dA = __expf(dl * a[n]);
      s[n] = fmaf(dA, s[n], du * bv[n]);
      y = fmaf(s[n], cv[n], y);
    }
    y = fmaf(u, Dd, y);
    float zz = bf2f(ldsZ[t * 64 + lane]);
    float sig = 1.f / (1.f + __expf(-zz));
    y *= zz * sig;
    y_b[(size_t)(c * 32 + t) * 2048 + d] = f2bf(y);
  }
}

// ---------------------------------------------------------------------------
extern "C" void kernel_launch(void* const* d_in, const int* in_sizes, int n_in,
                              void* d_out, int out_size, void* d_ws, size_t ws_size,
                              hipStream_t stream) {
  const float* x      = (const float*)d_in[0];
  const float* Win    = (const float*)d_in[1];
  const float* convw  = (const float*)d_in[2];
  const float* convb  = (const float*)d_in[3];
  const float* xprojw = (const float*)d_in[4];
  const float* dtw    = (const float*)d_in[5];
  const float* dtb    = (const float*)d_in[6];
  const float* Alog   = (const float*)d_in[7];
  const float* Dv     = (const float*)d_in[8];
  const float* Wout   = (const float*)d_in[9];
  float* out = (float*)d_out;

  char* ws = (char*)d_ws;
  size_t off = 0;
  auto alloc = [&](size_t bytes) -> void* {
    void* p = ws + off;
    off = (off + bytes + 255) & ~(size_t)255;
    return p;
  };
  unsigned short* xw_bf   = (unsigned short*)alloc((size_t)96 * 2048 * 2);
  unsigned short* dtw_bf  = (unsigned short*)alloc((size_t)2048 * 64 * 2);
  unsigned short* xz_bf   = (unsigned short*)alloc((size_t)1024 * 4096 * 2);
  unsigned short* xi_bf   = (unsigned short*)alloc((size_t)1024 * 2048 * 2);
  unsigned short* xd_bf   = (unsigned short*)alloc((size_t)1024 * 64 * 2);
  float* Bm               = (float*)alloc((size_t)1024 * 16 * 4);
  float* Cm               = (float*)alloc((size_t)1024 * 16 * 4);
  float* P                = (float*)alloc((size_t)32 * 16 * 2048 * 4);  // 4MB
  float* S                = (float*)alloc((size_t)32 * 16 * 2048 * 4);  // 4MB, contiguous after P
  float* SIn              = (float*)alloc((size_t)32 * 16 * 2048 * 4);
  unsigned short* y_bf    = (unsigned short*)alloc((size_t)1024 * 2048 * 2);
  // P,S dead after scan -> reused as split-K partials (contiguous 8MB).

  convert2<<<dim3(320), 256, 0, stream>>>(xprojw, xw_bf, 96 * 2048,
                                          dtw, dtw_bf, 2048 * 64);
  gemm64<1, 1, 1, 1><<<dim3(64, 16), 256, 0, stream>>>(
      x, Win, xz_bf, 1024, 4096, 1024);
  conv_silu<<<dim3(256), 256, 0, stream>>>(xz_bf, convw, convb, xi_bf);
  xproj<<<dim3(64, 6), 256, 0, stream>>>(xi_bf, xw_bf, xd_bf, Bm, Cm);
  scan_p1<<<dim3(32, 32), 64, 0, stream>>>(xd_bf, dtw_bf, dtb, xi_bf, Bm, Alog, P, S);
  scan_p2<<<dim3(128), 256, 0, stream>>>(P, S, SIn);
  scan_p3<<<dim3(32, 32), 64, 0, stream>>>(xd_bf, dtw_bf, dtb, xi_bf, Bm, Cm,
                                           Alog, Dv, SIn, xz_bf, y_bf);
  gemm64<0, 1, 2, 0><<<dim3(16, 16, 2), 256, 0, stream>>>(
      y_bf, Wout, P, 1024, 1024, 2048);
  reduce2<<<dim3(1024), 256, 0, stream>>>(P, out, 262144);
}

// Round 7
// 119.160 us; speedup vs baseline: 3.0214x; 1.0909x over previous
//
#include <hip/hip_runtime.h>
#include <hip/hip_bf16.h>
#include <cstdint>
#include <cstddef>

// ---------------------------------------------------------------------------
// Mamba block forward, MI355X (gfx950).  Round 7.
// Post-mortem r6: raw s_barrier + counted vmcnt RACED (s_barrier is not a
// compiler memory fence; replay-only divergence).  Reverted to the verified
// __syncthreads gemm structure (r2/r3-proven).
// Change this round: BK 64 -> 128 (halves K-iter count; per-iter barrier
// drain was ~2.9us).  in_proj: 8 iters.  out_proj: splitK=4, 4 iters,
// 1024 blocks.  Scan stays fused (r5-proven).
// ---------------------------------------------------------------------------

typedef __attribute__((ext_vector_type(4))) float f32x4;
typedef __attribute__((ext_vector_type(8))) short short8;

#define GLOAD_LDS16(g, l)                                                      \
  __builtin_amdgcn_global_load_lds(                                            \
      (const __attribute__((address_space(1))) void*)(g),                      \
      (__attribute__((address_space(3))) void*)(l), 16, 0, 0)

__device__ __forceinline__ unsigned short f2bf(float f) {
  union { float f; unsigned u; } v; v.f = f;
  unsigned u = v.u;
  unsigned r = (u + 0x7FFFu + ((u >> 16) & 1u)) >> 16;  // round-to-nearest-even
  return (unsigned short)r;
}
__device__ __forceinline__ float bf2f(unsigned short u) {
  union { unsigned u; float f; } v; v.u = ((unsigned)u) << 16;
  return v.f;
}

// ---------------------------------------------------------------------------
// fp32 -> bf16 conversion for 5 arrays (blockIdx.y picks the array)
// ---------------------------------------------------------------------------
__global__ __launch_bounds__(256) void convert_all(
    const float* __restrict__ a0, unsigned short* __restrict__ o0, int n0,
    const float* __restrict__ a1, unsigned short* __restrict__ o1, int n1,
    const float* __restrict__ a2, unsigned short* __restrict__ o2, int n2,
    const float* __restrict__ a3, unsigned short* __restrict__ o3, int n3,
    const float* __restrict__ a4, unsigned short* __restrict__ o4, int n4) {
  const float* a; unsigned short* o; int n;
  switch (blockIdx.y) {
    case 0: a = a0; o = o0; n = n0; break;
    case 1: a = a1; o = o1; n = n1; break;
    case 2: a = a2; o = o2; n = n2; break;
    case 3: a = a3; o = o3; n = n3; break;
    default: a = a4; o = o4; n = n4; break;
  }
  int n4c = n >> 2;
  int stride = gridDim.x * blockDim.x;
  for (int i = blockIdx.x * blockDim.x + threadIdx.x; i < n4c; i += stride) {
    float4 v = ((const float4*)a)[i];
    uint2 p;
    p.x = (unsigned)f2bf(v.x) | ((unsigned)f2bf(v.y) << 16);
    p.y = (unsigned)f2bf(v.z) | ((unsigned)f2bf(v.w) << 16);
    ((uint2*)o)[i] = p;
  }
}

// ---------------------------------------------------------------------------
// 64x64-tile bf16 GEMM, C = A @ B^T.  4 waves, 2x2 frags each, BK template
// (64 or 128).  Verified __syncthreads structure (r2/r3): stage tile0; sync;
// loop { prefetch next (gload_lds, lands under this iter's compute+sync);
// ds_read+MFMA; sync; }.  XOR swizzle on 16B k-slots (NS=BK/8 slots/row):
// inverse on global source, forward on ds_read.  XCD-chunked bijective
// block swizzle.  OBF: write C bf16.  SPLITK>1: partials at C + z*M*N.
// Requires M%64==0, N%64==0, (K/SPLITK)%BK==0, gridDim.x%8==0.
// ---------------------------------------------------------------------------
template <int BK, int SPLITK, int OBF>
__global__ __launch_bounds__(256) void gemm64(
    const unsigned short* __restrict__ A, const unsigned short* __restrict__ B,
    void* __restrict__ Cv, int M, int N, int K) {
  constexpr int NS = BK / 8;        // 16B slots per row
  constexpr int KS = BK / 32;       // k-steps per iter
  __shared__ unsigned short lds[2][2][64 * BK];
  const int tid  = threadIdx.x;
  const int lane = tid & 63;
  const int w    = tid >> 6;

  // bijective XCD-chunked swizzle
  const int nx = gridDim.x, ny = gridDim.y;
  int li = (blockIdx.z * ny + blockIdx.y) * nx + blockIdx.x;
  int xcd = li & 7, idx = li >> 3;
  int by = idx % ny;
  int r_ = idx / ny;
  int slab = nx >> 3;
  int bx = xcd * slab + (r_ % slab);
  int bz = r_ / slab;

  const int mBase = by * 64;
  const int nBase = bx * 64;
  const int kLen  = K / SPLITK;
  const int kBase = (SPLITK > 1) ? bz * kLen : 0;
  const int wr = (w >> 1) * 32;
  const int wc = (w & 1) * 32;

  auto stage = [&](int b, int k0) {
    #pragma unroll
    for (int j = 0; j < NS / 4; ++j) {
      int chunk = tid + j * 256;        // 16B chunks of the 64xBK tile
      int row = chunk / NS;
      int t = chunk % NS;               // physical slot in row
      int col = (t ^ (row & (NS - 1))) * 8;  // inverse swizzle on global src
      GLOAD_LDS16(&A[(size_t)(mBase + row) * K + k0 + col],
                  &lds[b][0][((size_t)(w * 64 + j * 256)) * 8]);
      GLOAD_LDS16(&B[(size_t)(nBase + row) * K + k0 + col],
                  &lds[b][1][((size_t)(w * 64 + j * 256)) * 8]);
    }
  };

  f32x4 acc[2][2];
  #pragma unroll
  for (int m = 0; m < 2; ++m)
    #pragma unroll
    for (int n = 0; n < 2; ++n)
      acc[m][n] = (f32x4){0.f, 0.f, 0.f, 0.f};

  const int kIters = kLen / BK;
  stage(0, kBase);
  __syncthreads();
  int buf = 0;
  for (int it = 0; it < kIters; ++it) {
    if (it + 1 < kIters) stage(buf ^ 1, kBase + (it + 1) * BK);
    short8 af[2][KS], bfr[2][KS];
    #pragma unroll
    for (int m = 0; m < 2; ++m)
      #pragma unroll
      for (int kk = 0; kk < KS; ++kk) {
        int row = wr + m * 16 + (lane & 15);
        int s = kk * 4 + (lane >> 4);
        af[m][kk] = *(const short8*)
            &lds[buf][0][row * BK + ((s ^ (row & (NS - 1))) * 8)];
      }
    #pragma unroll
    for (int n = 0; n < 2; ++n)
      #pragma unroll
      for (int kk = 0; kk < KS; ++kk) {
        int row = wc + n * 16 + (lane & 15);
        int s = kk * 4 + (lane >> 4);
        bfr[n][kk] = *(const short8*)
            &lds[buf][1][row * BK + ((s ^ (row & (NS - 1))) * 8)];
      }
    #pragma unroll
    for (int kk = 0; kk < KS; ++kk)
      #pragma unroll
      for (int m = 0; m < 2; ++m)
        #pragma unroll
        for (int n = 0; n < 2; ++n)
          acc[m][n] = __builtin_amdgcn_mfma_f32_16x16x32_bf16(
              af[m][kk], bfr[n][kk], acc[m][n], 0, 0, 0);
    __syncthreads();  // drains vmcnt(0): prefetch landed; buf reads done
    buf ^= 1;
  }

  if (OBF) {
    unsigned short* Cb = (unsigned short*)Cv;
    #pragma unroll
    for (int m = 0; m < 2; ++m) {
      int row0 = mBase + wr + m * 16 + (lane >> 4) * 4;
      #pragma unroll
      for (int n = 0; n < 2; ++n) {
        int col = nBase + wc + n * 16 + (lane & 15);
        #pragma unroll
        for (int r = 0; r < 4; ++r)
          Cb[(size_t)(row0 + r) * N + col] = f2bf(acc[m][n][r]);
      }
    }
  } else {
    float* Co = (float*)Cv + (SPLITK > 1 ? (size_t)bz * M * N : (size_t)0);
    #pragma unroll
    for (int m = 0; m < 2; ++m) {
      int row0 = mBase + wr + m * 16 + (lane >> 4) * 4;
      #pragma unroll
      for (int n = 0; n < 2; ++n) {
        int col = nBase + wc + n * 16 + (lane & 15);
        #pragma unroll
        for (int r = 0; r < 4; ++r)
          Co[(size_t)(row0 + r) * N + col] = acc[m][n][r];
      }
    }
  }
}

// out = sum of 4 split-K partials, vectorized
__global__ __launch_bounds__(256) void reduce4(
    const float* __restrict__ P, float* __restrict__ out, int n4) {
  int i = blockIdx.x * 256 + threadIdx.x;
  if (i < n4) {
    f32x4 a = ((const f32x4*)P)[i];
    f32x4 b = ((const f32x4*)P)[i + n4];
    f32x4 c = ((const f32x4*)P)[i + 2 * n4];
    f32x4 d = ((const f32x4*)P)[i + 3 * n4];
    ((f32x4*)out)[i] = (a + b) + (c + d);
  }
}

// ---------------------------------------------------------------------------
// causal depthwise conv (width 4) + silu, bf16 in (xz cols 0..2047) -> bf16 xi
// ---------------------------------------------------------------------------
__global__ __launch_bounds__(256) void conv_silu(
    const unsigned short* __restrict__ xz_bf, const float* __restrict__ cw,
    const float* __restrict__ cb, unsigned short* __restrict__ xi_b) {
  int d0 = threadIdx.x * 8;
  int l0 = blockIdx.x * 4;
  float wgt[8][4], bias[8];
  #pragma unroll
  for (int j = 0; j < 8; ++j) {
    float4 t = *(const float4*)&cw[(d0 + j) * 4];
    wgt[j][0] = t.x; wgt[j][1] = t.y; wgt[j][2] = t.z; wgt[j][3] = t.w;
  }
  *(float4*)(bias + 0) = *(const float4*)&cb[d0];
  *(float4*)(bias + 4) = *(const float4*)&cb[d0 + 4];

  short8 rows[7];
  #pragma unroll
  for (int r = 0; r < 7; ++r) {
    int ll = l0 - 3 + r;
    if (ll >= 0)
      rows[r] = *(const short8*)&xz_bf[(size_t)ll * 4096 + d0];
    else
      rows[r] = (short8){0, 0, 0, 0, 0, 0, 0, 0};
  }
  #pragma unroll
  for (int q = 0; q < 4; ++q) {
    short8 outv;
    #pragma unroll
    for (int j = 0; j < 8; ++j) {
      float acc = bias[j];
      #pragma unroll
      for (int k = 0; k < 4; ++k)
        acc = fmaf(bf2f((unsigned short)rows[q + k][j]), wgt[j][k], acc);
      float s = acc / (1.f + __expf(-acc));
      outv[j] = (short)f2bf(s);
    }
    *(short8*)&xi_b[(size_t)(l0 + q) * 2048 + d0] = outv;
  }
}

// ---------------------------------------------------------------------------
// x_dbl = xi @ x_proj_w^T  (M=1024, N=96, K=2048).  4 waves split K, LDS
// reduce.  cols 0..63 -> delta_raw (bf16), 64..79 -> Bm, 80..95 -> Cm (fp32)
// ---------------------------------------------------------------------------
__global__ __launch_bounds__(256) void xproj(
    const unsigned short* __restrict__ xi_b, const unsigned short* __restrict__ xw_b,
    unsigned short* __restrict__ xd_b, float* __restrict__ Bm, float* __restrict__ Cm) {
  __shared__ f32x4 red[4][64];
  int tid = threadIdx.x, lane = tid & 63, w = tid >> 6;
  int mt = blockIdx.x, nt = blockIdx.y;
  int arow = mt * 16 + (lane & 15);
  int brow = nt * 16 + (lane & 15);
  int kg = (lane >> 4) * 8;
  f32x4 acc = (f32x4){0.f, 0.f, 0.f, 0.f};
  for (int k0 = w * 512; k0 < (w + 1) * 512; k0 += 32) {
    short8 a = *(const short8*)&xi_b[(size_t)arow * 2048 + k0 + kg];
    short8 b = *(const short8*)&xw_b[(size_t)brow * 2048 + k0 + kg];
    acc = __builtin_amdgcn_mfma_f32_16x16x32_bf16(a, b, acc, 0, 0, 0);
  }
  red[w][lane] = acc;
  __syncthreads();
  if (w == 0) {
    acc = red[0][lane];
    acc += red[1][lane];
    acc += red[2][lane];
    acc += red[3][lane];
    int ocol = nt * 16 + (lane & 15);
    #pragma unroll
    for (int r = 0; r < 4; ++r) {
      int row = mt * 16 + (lane >> 4) * 4 + r;
      float v = acc[r];
      if (ocol < 64)      xd_b[row * 64 + ocol] = f2bf(v);
      else if (ocol < 80) Bm[row * 16 + (ocol - 64)] = v;
      else                Cm[row * 16 + (ocol - 80)] = v;
    }
  }
}

// ---------------------------------------------------------------------------
// dtproj tile (MFMA) -> ldsD.  Shared by scan_p1 / scan_p3.  One wave.
// ---------------------------------------------------------------------------
__device__ __forceinline__ void dt_tile(
    const unsigned short* __restrict__ xd, const unsigned short* __restrict__ dtw,
    const float* __restrict__ dtb, int c, int dblk, int lane,
    float* __restrict__ ldsD) {
  short8 afr[2][2], bfr4[4][2];
  #pragma unroll
  for (int lt = 0; lt < 2; ++lt)
    #pragma unroll
    for (int kk = 0; kk < 2; ++kk)
      afr[lt][kk] = *(const short8*)
          &xd[(size_t)(c * 32 + lt * 16 + (lane & 15)) * 64 + kk * 32 + (lane >> 4) * 8];
  #pragma unroll
  for (int dt = 0; dt < 4; ++dt)
    #pragma unroll
    for (int kk = 0; kk < 2; ++kk)
      bfr4[dt][kk] = *(const short8*)
          &dtw[(size_t)(dblk * 64 + dt * 16 + (lane & 15)) * 64 + kk * 32 + (lane >> 4) * 8];
  f32x4 acc[2][4];
  #pragma unroll
  for (int lt = 0; lt < 2; ++lt)
    #pragma unroll
    for (int dt = 0; dt < 4; ++dt)
      acc[lt][dt] = (f32x4){0.f, 0.f, 0.f, 0.f};
  #pragma unroll
  for (int kk = 0; kk < 2; ++kk)
    #pragma unroll
    for (int lt = 0; lt < 2; ++lt)
      #pragma unroll
      for (int dt = 0; dt < 4; ++dt)
        acc[lt][dt] = __builtin_amdgcn_mfma_f32_16x16x32_bf16(
            afr[lt][kk], bfr4[dt][kk], acc[lt][dt], 0, 0, 0);
  #pragma unroll
  for (int dt = 0; dt < 4; ++dt) {
    int dl_ = dt * 16 + (lane & 15);
    float bias = dtb[dblk * 64 + dl_];
    #pragma unroll
    for (int lt = 0; lt < 2; ++lt) {
      #pragma unroll
      for (int r = 0; r < 4; ++r) {
        int ll = lt * 16 + (lane >> 4) * 4 + r;
        float v = acc[lt][dt][r] + bias;
        float sp = (v > 20.f) ? v : log1pf(__expf(v));  // softplus
        ldsD[ll * 64 + dl_] = sp;
      }
    }
  }
}

// ---------------------------------------------------------------------------
// Chunked selective scan, 32 chunks x 32 steps.  Block (dblk, c) = 1 wave.
// ---------------------------------------------------------------------------
__global__ __launch_bounds__(64) void scan_p1(
    const unsigned short* __restrict__ xd, const unsigned short* __restrict__ dtw,
    const float* __restrict__ dtb, const unsigned short* __restrict__ xi,
    const float* __restrict__ BmG, const float* __restrict__ Alog,
    float* __restrict__ P, float* __restrict__ S) {
  __shared__ float ldsD[32 * 64];          // delta [t][d]  8KB
  __shared__ unsigned short ldsU[32 * 64]; // u     [t][d]  4KB
  __shared__ float ldsB[32 * 16];          // B     [t][n]  2KB
  const int dblk = blockIdx.x, c = blockIdx.y;
  const int lane = threadIdx.x;
  const int d = dblk * 64 + lane;

  #pragma unroll
  for (int i = 0; i < 8; ++i)
    ldsB[lane + i * 64] = BmG[c * 512 + lane + i * 64];
  #pragma unroll
  for (int i = 0; i < 4; ++i) {   // u tile, 16B chunks
    int chunk = lane + i * 64;
    int row = chunk >> 3, c8 = chunk & 7;
    *(int4*)&ldsU[row * 64 + c8 * 8] =
        *(const int4*)&xi[(size_t)(c * 32 + row) * 2048 + dblk * 64 + c8 * 8];
  }
  dt_tile(xd, dtw, dtb, c, dblk, lane, ldsD);
  __syncthreads();

  float a[16], p[16], s[16];
  #pragma unroll
  for (int n = 0; n < 16; ++n) {
    a[n] = -__expf(Alog[d * 16 + n]);
    p[n] = 1.f; s[n] = 0.f;
  }
  for (int t = 0; t < 32; ++t) {
    float dl = ldsD[t * 64 + lane];
    float u  = bf2f(ldsU[t * 64 + lane]);
    float du = dl * u;
    float bv[16];
    *(float4*)(bv + 0)  = *(const float4*)&ldsB[t * 16 + 0];
    *(float4*)(bv + 4)  = *(const float4*)&ldsB[t * 16 + 4];
    *(float4*)(bv + 8)  = *(const float4*)&ldsB[t * 16 + 8];
    *(float4*)(bv + 12) = *(const float4*)&ldsB[t * 16 + 12];
    #pragma unroll
    for (int n = 0; n < 16; ++n) {
      float dA = __expf(dl * a[n]);
      s[n] = fmaf(dA, s[n], du * bv[n]);
      p[n] *= dA;
    }
  }
  #pragma unroll
  for (int n = 0; n < 16; ++n) {
    P[(size_t)(c * 16 + n) * 2048 + d] = p[n];
    S[(size_t)(c * 16 + n) * 2048 + d] = s[n];
  }
}

__global__ __launch_bounds__(256) void scan_p2(
    const float* __restrict__ P, const float* __restrict__ S,
    float* __restrict__ SIn) {
  int idx = blockIdx.x * 256 + threadIdx.x;  // 0..32767 = n*2048+d
  float sin_ = 0.f;
  #pragma unroll 4
  for (int c = 0; c < 32; ++c) {
    SIn[c * 32768 + idx] = sin_;
    sin_ = fmaf(P[c * 32768 + idx], sin_, S[c * 32768 + idx]);
  }
}

__global__ __launch_bounds__(64) void scan_p3(
    const unsigned short* __restrict__ xd, const unsigned short* __restrict__ dtw,
    const float* __restrict__ dtb, const unsigned short* __restrict__ xi,
    const float* __restrict__ BmG, const float* __restrict__ CmG,
    const float* __restrict__ Alog, const float* __restrict__ Dv,
    const float* __restrict__ SIn, const unsigned short* __restrict__ xz,
    unsigned short* __restrict__ y_b) {
  __shared__ float ldsD[32 * 64];
  __shared__ unsigned short ldsU[32 * 64];
  __shared__ unsigned short ldsZ[32 * 64];
  __shared__ float ldsB[32 * 16];
  __shared__ float ldsC[32 * 16];
  const int dblk = blockIdx.x, c = blockIdx.y;
  const int lane = threadIdx.x;
  const int d = dblk * 64 + lane;

  #pragma unroll
  for (int i = 0; i < 8; ++i) {
    ldsB[lane + i * 64] = BmG[c * 512 + lane + i * 64];
    ldsC[lane + i * 64] = CmG[c * 512 + lane + i * 64];
  }
  #pragma unroll
  for (int i = 0; i < 4; ++i) {
    int chunk = lane + i * 64;
    int row = chunk >> 3, c8 = chunk & 7;
    *(int4*)&ldsU[row * 64 + c8 * 8] =
        *(const int4*)&xi[(size_t)(c * 32 + row) * 2048 + dblk * 64 + c8 * 8];
    *(int4*)&ldsZ[row * 64 + c8 * 8] =
        *(const int4*)&xz[(size_t)(c * 32 + row) * 4096 + 2048 + dblk * 64 + c8 * 8];
  }
  dt_tile(xd, dtw, dtb, c, dblk, lane, ldsD);
  __syncthreads();

  float a[16], s[16];
  #pragma unroll
  for (int n = 0; n < 16; ++n) {
    a[n] = -__expf(Alog[d * 16 + n]);
    s[n] = SIn[c * 32768 + n * 2048 + d];
  }
  float Dd = Dv[d];
  for (int t = 0; t < 32; ++t) {
    float dl = ldsD[t * 64 + lane];
    float u  = bf2f(ldsU[t * 64 + lane]);
    float du = dl * u;
    float bv[16], cv[16];
    *(float4*)(bv + 0)  = *(const float4*)&ldsB[t * 16 + 0];
    *(float4*)(bv + 4)  = *(const float4*)&ldsB[t * 16 + 4];
    *(float4*)(bv + 8)  = *(const float4*)&ldsB[t * 16 + 8];
    *(float4*)(bv + 12) = *(const float4*)&ldsB[t * 16 + 12];
    *(float4*)(cv + 0)  = *(const float4*)&ldsC[t * 16 + 0];
    *(float4*)(cv + 4)  = *(const float4*)&ldsC[t * 16 + 4];
    *(float4*)(cv + 8)  = *(const float4*)&ldsC[t * 16 + 8];
    *(float4*)(cv + 12) = *(const float4*)&ldsC[t * 16 + 12];
    float y = 0.f;
    #pragma unroll
    for (int n = 0; n < 16; ++n) {
      float dA = __expf(dl * a[n]);
      s[n] = fmaf(dA, s[n], du * bv[n]);
      y = fmaf(s[n], cv[n], y);
    }
    y = fmaf(u, Dd, y);
    float zz = bf2f(ldsZ[t * 64 + lane]);
    float sig = 1.f / (1.f + __expf(-zz));
    y *= zz * sig;
    y_b[(size_t)(c * 32 + t) * 2048 + d] = f2bf(y);
  }
}

// ---------------------------------------------------------------------------
extern "C" void kernel_launch(void* const* d_in, const int* in_sizes, int n_in,
                              void* d_out, int out_size, void* d_ws, size_t ws_size,
                              hipStream_t stream) {
  const float* x      = (const float*)d_in[0];
  const float* Win    = (const float*)d_in[1];
  const float* convw  = (const float*)d_in[2];
  const float* convb  = (const float*)d_in[3];
  const float* xprojw = (const float*)d_in[4];
  const float* dtw    = (const float*)d_in[5];
  const float* dtb    = (const float*)d_in[6];
  const float* Alog   = (const float*)d_in[7];
  const float* Dv     = (const float*)d_in[8];
  const float* Wout   = (const float*)d_in[9];
  float* out = (float*)d_out;

  char* ws = (char*)d_ws;
  size_t off = 0;
  auto alloc = [&](size_t bytes) -> void* {
    void* p = ws + off;
    off = (off + bytes + 255) & ~(size_t)255;
    return p;
  };
  unsigned short* x_bf    = (unsigned short*)alloc((size_t)1024 * 1024 * 2);
  unsigned short* Win_bf  = (unsigned short*)alloc((size_t)4096 * 1024 * 2);
  unsigned short* Wout_bf = (unsigned short*)alloc((size_t)1024 * 2048 * 2);
  unsigned short* xw_bf   = (unsigned short*)alloc((size_t)96 * 2048 * 2);
  unsigned short* dtw_bf  = (unsigned short*)alloc((size_t)2048 * 64 * 2);
  unsigned short* xz_bf   = (unsigned short*)alloc((size_t)1024 * 4096 * 2);
  unsigned short* xi_bf   = (unsigned short*)alloc((size_t)1024 * 2048 * 2);
  unsigned short* xd_bf   = (unsigned short*)alloc((size_t)1024 * 64 * 2);
  float* Bm               = (float*)alloc((size_t)1024 * 16 * 4);
  float* Cm               = (float*)alloc((size_t)1024 * 16 * 4);
  float* P                = (float*)alloc((size_t)32 * 16 * 2048 * 4);  // 4MB
  float* S                = (float*)alloc((size_t)32 * 16 * 2048 * 4);  // 4MB
  float* SIn              = (float*)alloc((size_t)32 * 16 * 2048 * 4);  // 4MB
  unsigned short* y_bf    = (unsigned short*)alloc((size_t)1024 * 2048 * 2);
  float* part4            = (float*)alloc((size_t)4 * 1024 * 1024 * 4); // 16MB

  convert_all<<<dim3(512, 5), 256, 0, stream>>>(
      x, x_bf, 1024 * 1024,
      Win, Win_bf, 4096 * 1024,
      Wout, Wout_bf, 1024 * 2048,
      xprojw, xw_bf, 96 * 2048,
      dtw, dtw_bf, 2048 * 64);
  gemm64<128, 1, 1><<<dim3(64, 16), 256, 0, stream>>>(
      x_bf, Win_bf, xz_bf, 1024, 4096, 1024);
  conv_silu<<<dim3(256), 256, 0, stream>>>(xz_bf, convw, convb, xi_bf);
  xproj<<<dim3(64, 6), 256, 0, stream>>>(xi_bf, xw_bf, xd_bf, Bm, Cm);
  scan_p1<<<dim3(32, 32), 64, 0, stream>>>(xd_bf, dtw_bf, dtb, xi_bf, Bm, Alog, P, S);
  scan_p2<<<dim3(128), 256, 0, stream>>>(P, S, SIn);
  scan_p3<<<dim3(32, 32), 64, 0, stream>>>(xd_bf, dtw_bf, dtb, xi_bf, Bm, Cm,
                                           Alog, Dv, SIn, xz_bf, y_bf);
  gemm64<128, 4, 0><<<dim3(16, 16, 4), 256, 0, stream>>>(
      y_bf, Wout_bf, part4, 1024, 1024, 2048);
  reduce4<<<dim3(1024), 256, 0, stream>>>(part4, out, 262144);
}